// Round 4
// baseline (166.262 us; speedup 1.0000x reference)
//
#include <hip/hip_runtime.h>
#include <hip/hip_bf16.h>

// Problem: B=2048, IN_DIM=1024, HID=512, FEAT=256, all fp32.
//   h_b = relu(x_b @ W_feat + b_feat); f_b = h_b @ W_br_b + b_br_b
//   out[b,c] = sum_{j,i} f1[j] f0[i] W_out[j*256+i, c] + b_out[c]
// Kron trick: W_out viewed as Wr[256,512]: t = f1 @ Wr;
//   out[b,c] = sum_i f0[b,i] * t[b, i*2+c] + b_out[c]
// R4 fold: t = h1 @ Wc + bc where Wc = W_br1@Wr, bc = b_br1@Wr (weight-only).
// Pipeline: prep -> G1{h0,h1,Wc} -> G2{f0,t} -> kron.  4 launches.

typedef __attribute__((ext_vector_type(8))) short bf16x8;
typedef __attribute__((ext_vector_type(4))) float f32x4;
typedef unsigned short u16;

#define LS 72   // LDS row stride (64+8 pad): 144 B -> 2-way bank alias (free, m136)

__device__ __forceinline__ u16 f2bf(float f) {
    unsigned int u = __float_as_uint(f);
    return (u16)((u + 0x7FFFu + ((u >> 16) & 1u)) >> 16);   // RNE
}
__device__ __forceinline__ float bf2f(u16 h) {
    return __uint_as_float(((unsigned int)h) << 16);
}

// ---------------- prep: x->bf16, weight transposes/converts, bc ----------------
// blocks: [0,2048) x convert ; [2048,4096) WfT ; [4096,4608) Wb0T ;
//         [4608,5120) WrT ; [5120,5184) Wb1c ; [5184,5186) bc.
__global__ __launch_bounds__(256) void prep(
    const float* __restrict__ x0, u16* __restrict__ xb0,
    const float* __restrict__ x1, u16* __restrict__ xb1,
    const float* __restrict__ W_feat, u16* __restrict__ WfT,
    const float* __restrict__ W_br0,  u16* __restrict__ Wb0T,
    const float* __restrict__ W_out,  u16* __restrict__ WrT,
    const float* __restrict__ W_br1,  u16* __restrict__ Wb1c,
    const float* __restrict__ b_br1,  float* __restrict__ bc)
{
    const int bx = blockIdx.x, tid = threadIdx.x;
    if (bx < 2048) {                       // x0/x1 -> bf16, 8 elems/thread
        const float* s = (bx < 1024) ? x0 : x1;
        u16* d = (bx < 1024) ? xb0 : xb1;
        int idx = ((bx & 1023) * 256 + tid) * 8;
        float4 a = *(const float4*)&s[idx];
        float4 b = *(const float4*)&s[idx + 4];
        ushort4 ha; ha.x = f2bf(a.x); ha.y = f2bf(a.y); ha.z = f2bf(a.z); ha.w = f2bf(a.w);
        ushort4 hb; hb.x = f2bf(b.x); hb.y = f2bf(b.y); hb.z = f2bf(b.z); hb.w = f2bf(b.w);
        *(ushort4*)&d[idx] = ha;
        *(ushort4*)&d[idx + 4] = hb;
    } else if (bx < 4096) {                // WfT[n][k] = W_feat[k][n], 512x1024
        int local = (bx - 2048) * 256 + tid;
        int k = local & 1023, n = local >> 10;
        WfT[local] = f2bf(W_feat[(size_t)k * 512 + n]);
    } else if (bx < 4608) {                // Wb0T[n][k] = W_br0[k][n], 256x512
        int local = (bx - 4096) * 256 + tid;
        int k = local & 511, n = local >> 9;
        Wb0T[local] = f2bf(W_br0[(size_t)k * 256 + n]);
    } else if (bx < 5120) {                // WrT[n][j] = Wr[j][n], 512x256
        int local = (bx - 4608) * 256 + tid;
        int j = local & 255, n = local >> 8;
        WrT[local] = f2bf(W_out[(size_t)j * 512 + n]);
    } else if (bx < 5184) {                // Wb1c = bf16(W_br1), straight
        int idx = ((bx - 5120) * 256 + tid) * 8;
        float4 a = *(const float4*)&W_br1[idx];
        float4 b = *(const float4*)&W_br1[idx + 4];
        ushort4 ha; ha.x = f2bf(a.x); ha.y = f2bf(a.y); ha.z = f2bf(a.z); ha.w = f2bf(a.w);
        ushort4 hb; hb.x = f2bf(b.x); hb.y = f2bf(b.y); hb.z = f2bf(b.z); hb.w = f2bf(b.w);
        *(ushort4*)&Wb1c[idx] = ha;
        *(ushort4*)&Wb1c[idx + 4] = hb;
    } else {                               // bc[n] = sum_j b_br1[j]*Wr[j][n]
        int n = (bx - 5184) * 256 + tid;
        float acc = 0.0f;
        for (int j = 0; j < 256; ++j) acc += b_br1[j] * W_out[(size_t)j * 512 + n];
        bc[n] = acc;
    }
}

// ---------------- multi-descriptor bf16 MFMA GEMM ----------------
// C = [relu](A @ W + bias). A: [M,K] bf16. WT: [N,K] bf16 (n-major).
// 64x64 tile, BK=64, 4 waves of 32x32 (2x2 frags, 16x16x32), 2-deep prefetch.
struct GemmDesc {
    const u16* A; const u16* WT; const float* bias; void* C;
    int K; int N; int n_tiles; int flags;   // flags: 1=relu, 2=out_bf16
};

__global__ __launch_bounds__(256) void gemm_multi(
    GemmDesc da, GemmDesc db, GemmDesc dc, int s1, int s2)
{
    const int bx = blockIdx.x;
    const u16* A; const u16* WT; const float* bias; void* Cv;
    int K, N, nt, flags, local;
    if (bx < s1) {
        A = da.A; WT = da.WT; bias = da.bias; Cv = da.C;
        K = da.K; N = da.N; nt = da.n_tiles; flags = da.flags; local = bx;
    } else if (bx < s2) {
        A = db.A; WT = db.WT; bias = db.bias; Cv = db.C;
        K = db.K; N = db.N; nt = db.n_tiles; flags = db.flags; local = bx - s1;
    } else {
        A = dc.A; WT = dc.WT; bias = dc.bias; Cv = dc.C;
        K = dc.K; N = dc.N; nt = dc.n_tiles; flags = dc.flags; local = bx - s2;
    }
    const int bn = (local % nt) * 64;
    const int bm = (local / nt) * 64;

    __shared__ __align__(16) u16 As[64 * LS];
    __shared__ __align__(16) u16 Ws[64 * LS];

    const int tid  = threadIdx.x;
    const int lane = tid & 63;
    const int wave = tid >> 6;
    const int wr   = wave >> 1;
    const int wc   = wave & 1;
    const int lrow = lane & 15;
    const int quad = lane >> 4;

    const int r0 = tid >> 3;           // 0..31
    const int r1 = r0 + 32;
    const int k8 = (tid & 7) * 8;

    const u16* pA0 = A  + (size_t)(bm + r0) * K + k8;
    const u16* pA1 = A  + (size_t)(bm + r1) * K + k8;
    const u16* pW0 = WT + (size_t)(bn + r0) * K + k8;
    const u16* pW1 = WT + (size_t)(bn + r1) * K + k8;

    f32x4 acc[2][2] = {};
    int4 rA0[2], rA1[2], rW0[2], rW1[2];

    // tile 0 -> set 0, stage to LDS
    rA0[0] = *(const int4*)pA0;  rA1[0] = *(const int4*)pA1;
    rW0[0] = *(const int4*)pW0;  rW1[0] = *(const int4*)pW1;
    *(int4*)&As[r0 * LS + k8] = rA0[0];
    *(int4*)&As[r1 * LS + k8] = rA1[0];
    *(int4*)&Ws[r0 * LS + k8] = rW0[0];
    *(int4*)&Ws[r1 * LS + k8] = rW1[0];
    // tile 1 -> set 1 (in flight across tile-0 compute)
    if (64 < K) {
        rA0[1] = *(const int4*)(pA0 + 64);  rA1[1] = *(const int4*)(pA1 + 64);
        rW0[1] = *(const int4*)(pW0 + 64);  rW1[1] = *(const int4*)(pW1 + 64);
    }
    __syncthreads();

    int cur = 1;
    for (int kk = 0; kk < K; kk += 64) {
        #pragma unroll
        for (int ks = 0; ks < 2; ++ks) {
            const int k0 = ks * 32 + quad * 8;
            bf16x8 a0 = *(const bf16x8*)&As[(wr * 32 +      lrow) * LS + k0];
            bf16x8 a1 = *(const bf16x8*)&As[(wr * 32 + 16 + lrow) * LS + k0];
            bf16x8 b0 = *(const bf16x8*)&Ws[(wc * 32 +      lrow) * LS + k0];
            bf16x8 b1 = *(const bf16x8*)&Ws[(wc * 32 + 16 + lrow) * LS + k0];
            acc[0][0] = __builtin_amdgcn_mfma_f32_16x16x32_bf16(a0, b0, acc[0][0], 0, 0, 0);
            acc[0][1] = __builtin_amdgcn_mfma_f32_16x16x32_bf16(a0, b1, acc[0][1], 0, 0, 0);
            acc[1][0] = __builtin_amdgcn_mfma_f32_16x16x32_bf16(a1, b0, acc[1][0], 0, 0, 0);
            acc[1][1] = __builtin_amdgcn_mfma_f32_16x16x32_bf16(a1, b1, acc[1][1], 0, 0, 0);
        }
        const int pf = kk + 128;
        const int ns = cur ^ 1;
        if (pf < K) {               // 2-deep: tile k+2 in flight across next compute
            rA0[ns] = *(const int4*)(pA0 + pf);  rA1[ns] = *(const int4*)(pA1 + pf);
            rW0[ns] = *(const int4*)(pW0 + pf);  rW1[ns] = *(const int4*)(pW1 + pf);
        }
        if (kk + 64 < K) {
            __syncthreads();
            *(int4*)&As[r0 * LS + k8] = rA0[cur];
            *(int4*)&As[r1 * LS + k8] = rA1[cur];
            *(int4*)&Ws[r0 * LS + k8] = rW0[cur];
            *(int4*)&Ws[r1 * LS + k8] = rW1[cur];
            __syncthreads();
            cur = ns;
        }
    }

    // C/D layout: col=lane&15, row=quad*4+reg (verified m89/m91).
    #pragma unroll
    for (int fm = 0; fm < 2; ++fm) {
        #pragma unroll
        for (int fn = 0; fn < 2; ++fn) {
            const int c = bn + wc * 32 + fn * 16 + lrow;
            const float bv = bias ? bias[c] : 0.0f;
            #pragma unroll
            for (int reg = 0; reg < 4; ++reg) {
                const int r = bm + wr * 32 + fm * 16 + quad * 4 + reg;
                float v = acc[fm][fn][reg] + bv;
                if (flags & 1) v = fmaxf(v, 0.0f);
                if (flags & 2) ((u16*)Cv)[(size_t)r * N + c] = f2bf(v);
                else           ((float*)Cv)[(size_t)r * N + c] = v;
            }
        }
    }
}

// out[b,c] = sum_i f0[b,i] * t[b, i*2+c] + b_out[c]; one block per row b.
__global__ __launch_bounds__(256) void kron_reduce(
    const u16* __restrict__ f0, const float* __restrict__ t,
    const float* __restrict__ b_out, float* __restrict__ out)
{
    const int b = blockIdx.x;
    const int i = threadIdx.x;
    const float  v  = bf2f(f0[(size_t)b * 256 + i]);
    const float2 tv = ((const float2*)(t + (size_t)b * 512))[i];
    float p0 = v * tv.x;
    float p1 = v * tv.y;
    #pragma unroll
    for (int off = 32; off > 0; off >>= 1) {
        p0 += __shfl_down(p0, off);
        p1 += __shfl_down(p1, off);
    }
    __shared__ float s0[4], s1[4];
    const int wv = i >> 6;
    if ((i & 63) == 0) { s0[wv] = p0; s1[wv] = p1; }
    __syncthreads();
    if (i == 0) {
        out[(size_t)b * 2 + 0] = s0[0] + s0[1] + s0[2] + s0[3] + b_out[0];
        out[(size_t)b * 2 + 1] = s1[0] + s1[1] + s1[2] + s1[3] + b_out[1];
    }
}

extern "C" void kernel_launch(void* const* d_in, const int* in_sizes, int n_in,
                              void* d_out, int out_size, void* d_ws, size_t ws_size,
                              hipStream_t stream) {
    const float* x0     = (const float*)d_in[0];
    const float* x1     = (const float*)d_in[1];
    const float* W_feat = (const float*)d_in[2];
    const float* b_feat = (const float*)d_in[3];
    const float* W_br0  = (const float*)d_in[4];
    const float* b_br0  = (const float*)d_in[5];
    const float* W_br1  = (const float*)d_in[6];
    const float* b_br1  = (const float*)d_in[7];
    const float* W_out  = (const float*)d_in[8];
    const float* b_out  = (const float*)d_in[9];
    float* out = (float*)d_out;

    u16* ws   = (u16*)d_ws;
    u16* xb0  = ws;                       // 2048x1024
    u16* xb1  = xb0  + 2097152;
    u16* WfT  = xb1  + 2097152;           // 512x1024
    u16* Wb0T = WfT  + 524288;            // 256x512
    u16* WrT  = Wb0T + 131072;            // 512x256
    u16* Wb1c = WrT  + 131072;            // 512x256 (W_br1 bf16, natural layout)
    u16* WcT  = Wb1c + 131072;            // 512x512 (Wc^T, n-major)
    u16* h0   = WcT  + 262144;            // 2048x512 bf16
    u16* h1   = h0   + 1048576;
    u16* f0   = h1   + 1048576;           // 2048x256 bf16
    float* t  = (float*)(f0 + 524288);    // 2048x512 fp32
    float* bc = t + 1048576;              // 512 fp32

    dim3 blk(256);

    // 1) prep: converts + transposes + bc               (5186 blocks)
    prep<<<dim3(5186), blk, 0, stream>>>(
        x0, xb0, x1, xb1, W_feat, WfT, W_br0, Wb0T, W_out, WrT,
        W_br1, Wb1c, b_br1, bc);

    // 2) G1: h0, h1 (K=1024, relu, bf16 out) + WcT = (Wr^T @ W_br1^T) (K=256)
    //    WcT gemm: A=WrT [512,256], WT=Wb1c [512,256] -> C[n][k] row-major = WcT.
    GemmDesc g1a = { xb0, WfT, b_feat, h0, 1024, 512, 8, 3 };
    GemmDesc g1b = { xb1, WfT, b_feat, h1, 1024, 512, 8, 3 };
    GemmDesc g1c = { WrT, Wb1c, nullptr, WcT, 256, 512, 8, 2 };
    gemm_multi<<<dim3(256 + 256 + 64), blk, 0, stream>>>(g1a, g1b, g1c, 256, 512);

    // 3) G2: f0 = h0 @ W_br0 + b_br0 (K=512, bf16 out)
    //        t  = h1 @ Wc + bc       (K=512, fp32 out)
    GemmDesc g2a = { h0, Wb0T, b_br0, f0, 512, 256, 4, 2 };
    GemmDesc g2b = { h1, WcT, bc, t, 512, 512, 8, 0 };
    gemm_multi<<<dim3(128 + 256), blk, 0, stream>>>(g2a, g2b, g2b, 128, 384);

    // 4) out[b,c] = sum_i f0[b,i]*t[b,i*2+c] + b_out[c]
    kron_reduce<<<dim3(2048), blk, 0, stream>>>(f0, t, b_out, out);
}

// Round 5
// 121.346 us; speedup vs baseline: 1.3701x; 1.3701x over previous
//
#include <hip/hip_runtime.h>
#include <hip/hip_bf16.h>

// B=2048, IN=1024, HID=512, FEAT=256, fp32 in/out.
//   h_b = relu(x_b @ W_feat + b_feat); f0 = h0 @ W_br0 + b_br0
//   Kron trick + fold: t = h1 @ Wc + bc, Wc = W_br1 @ Wr, bc = b_br1 @ Wr
//   out[b,c] = sum_i f0[b,i] * t[b, i*2+c] + b_out[c]
// R5: barrier-free wave-GEMM. Operands pre-packed in MFMA fragment-major
// ("FS") layout: chunk(mt,kt,lane) = X[mt*16+(lane&15)][kt*32+(lane>>4)*8 ..+7]
// so the K-loop is pure global_load_dwordx4 + mfma, no LDS, no __syncthreads
// (kills the vmcnt(0)-before-barrier drain that capped R2-R4 at MfmaUtil ~3%).

typedef __attribute__((ext_vector_type(8))) short bf16x8;
typedef __attribute__((ext_vector_type(4))) float f32x4;
typedef unsigned short u16;

__device__ __forceinline__ u16 f2bf(float f) {
    unsigned int u = __float_as_uint(f);
    return (u16)((u + 0x7FFFu + ((u >> 16) & 1u)) >> 16);   // RNE
}
__device__ __forceinline__ float bf2f(u16 h) {
    return __uint_as_float(((unsigned int)h) << 16);
}

// ---- FS packers: one thread = one 16B chunk (8 bf16) ----
// rows-major source S[R][1<<lgK]: contiguous 8 along k.
__device__ __forceinline__ void fs_rm(const float* __restrict__ src,
                                      u16* __restrict__ dst, int lgK, int c) {
    const int lane = c & 63, t = c >> 6;
    const int kt = t & ((1 << (lgK - 5)) - 1);
    const int mt = t >> (lgK - 5);
    const int m = mt * 16 + (lane & 15);
    const int k = kt * 32 + (lane >> 4) * 8;
    const float* p = src + ((size_t)m << lgK) + k;
    float4 v0 = *(const float4*)p;
    float4 v1 = *(const float4*)(p + 4);
    ushort4 h0; h0.x = f2bf(v0.x); h0.y = f2bf(v0.y); h0.z = f2bf(v0.z); h0.w = f2bf(v0.w);
    ushort4 h1; h1.x = f2bf(v1.x); h1.y = f2bf(v1.y); h1.z = f2bf(v1.z); h1.w = f2bf(v1.w);
    *(ushort4*)&dst[(size_t)c * 8]     = h0;
    *(ushort4*)&dst[(size_t)c * 8 + 4] = h1;
}
// column source: FS rows index the 2nd dim of W[K][N] (value = W[k][n]).
__device__ __forceinline__ void fs_cm(const float* __restrict__ src,
                                      u16* __restrict__ dst, int N, int lgK, int c) {
    const int lane = c & 63, t = c >> 6;
    const int kt = t & ((1 << (lgK - 5)) - 1);
    const int mt = t >> (lgK - 5);
    const int n = mt * 16 + (lane & 15);
    const int k = kt * 32 + (lane >> 4) * 8;
    u16 b[8];
    #pragma unroll
    for (int j = 0; j < 8; ++j) b[j] = f2bf(src[(size_t)(k + j) * N + n]);
    *(ushort4*)&dst[(size_t)c * 8]     = *(ushort4*)&b[0];
    *(ushort4*)&dst[(size_t)c * 8 + 4] = *(ushort4*)&b[4];
}

// prep: all converts/packs + bc.  Block ranges:
// [0,1024) xb0 | [1024,2048) xb1 | [2048,2304) WfT | [2304,2368) Wb0T |
// [2368,2432) WrT | [2432,2496) Wb1c | [2496,2498) bc
__global__ __launch_bounds__(256) void prep(
    const float* __restrict__ x0, u16* __restrict__ xb0,
    const float* __restrict__ x1, u16* __restrict__ xb1,
    const float* __restrict__ W_feat, u16* __restrict__ WfT,
    const float* __restrict__ W_br0,  u16* __restrict__ Wb0T,
    const float* __restrict__ W_out,  u16* __restrict__ WrT,
    const float* __restrict__ W_br1,  u16* __restrict__ Wb1c,
    const float* __restrict__ b_br1,  float* __restrict__ bc)
{
    const int bx = blockIdx.x, tid = threadIdx.x;
    if (bx < 1024)      fs_rm(x0, xb0, 10, bx * 256 + tid);
    else if (bx < 2048) fs_rm(x1, xb1, 10, (bx - 1024) * 256 + tid);
    else if (bx < 2304) fs_cm(W_feat, WfT, 512, 10, (bx - 2048) * 256 + tid);
    else if (bx < 2368) fs_cm(W_br0, Wb0T, 256, 9, (bx - 2304) * 256 + tid);
    else if (bx < 2432) fs_cm(W_out, WrT, 512, 8, (bx - 2368) * 256 + tid);  // A-view of Wr^T
    else if (bx < 2496) fs_rm(W_br1, Wb1c, 8, (bx - 2432) * 256 + tid);      // B-view of Wc-gemm
    else {                                   // bc[n] = sum_j b_br1[j]*Wr[j][n]
        int n = (bx - 2496) * 256 + tid;
        float a = 0.0f;
        #pragma unroll 8
        for (int j = 0; j < 256; ++j) a += b_br1[j] * W_out[(size_t)j * 512 + n];
        bc[n] = a;
    }
}

// ---- barrier-free wave GEMM ----
// One wave computes a 32x32 output tile: 2x2 frags of 16x16x32 bf16 MFMA.
// A, B in FS layout. flags: 1=relu, 2=bf16 row-major out, 4=FS bf16 out.
struct GD {
    const u16* A; const u16* B; const float* bias; void* C;
    int K32;    // K/32
    int ntiles; // N/32 (even)
    int N;      // output cols (row stride); for FS out: K-dim of output
    int flags;
};

__global__ __launch_bounds__(256) void gemm_wave(GD d0, GD d1, GD d2, int s1, int s2)
{
    const int wid  = blockIdx.x * 4 + (threadIdx.x >> 6);
    const int lane = threadIdx.x & 63;
    const int lrow = lane & 15;
    const int quad = lane >> 4;

    GD d; int local;
    if (wid < s1)      { d = d0; local = wid; }
    else if (wid < s2) { d = d1; local = wid - s1; }
    else               { d = d2; local = wid - s2; }

    // 2x2 wave grouping per block for L1/L2 stream reuse
    const int half = d.ntiles >> 1;
    const int st = local >> 2, sub = local & 3;
    const int tm = (st / half) * 2 + (sub >> 1);
    const int tn = (st % half) * 2 + (sub & 1);
    const int K32 = d.K32;

    const u16* pa0 = d.A + (((size_t)(2 * tm) * K32) * 64 + lane) * 8;
    const u16* pa1 = pa0 + (size_t)K32 * 512;
    const u16* pb0 = d.B + (((size_t)(2 * tn) * K32) * 64 + lane) * 8;
    const u16* pb1 = pb0 + (size_t)K32 * 512;

    f32x4 acc00 = {}, acc01 = {}, acc10 = {}, acc11 = {};

    bf16x8 ca0 = *(const bf16x8*)pa0;
    bf16x8 ca1 = *(const bf16x8*)pa1;
    bf16x8 cb0 = *(const bf16x8*)pb0;
    bf16x8 cb1 = *(const bf16x8*)pb1;

    #pragma unroll 4
    for (int s = 0; s < K32; ++s) {
        const int sn = (s + 1 < K32) ? s + 1 : s;
        bf16x8 na0 = *(const bf16x8*)(pa0 + (size_t)sn * 512);
        bf16x8 na1 = *(const bf16x8*)(pa1 + (size_t)sn * 512);
        bf16x8 nb0 = *(const bf16x8*)(pb0 + (size_t)sn * 512);
        bf16x8 nb1 = *(const bf16x8*)(pb1 + (size_t)sn * 512);
        acc00 = __builtin_amdgcn_mfma_f32_16x16x32_bf16(ca0, cb0, acc00, 0, 0, 0);
        acc01 = __builtin_amdgcn_mfma_f32_16x16x32_bf16(ca0, cb1, acc01, 0, 0, 0);
        acc10 = __builtin_amdgcn_mfma_f32_16x16x32_bf16(ca1, cb0, acc10, 0, 0, 0);
        acc11 = __builtin_amdgcn_mfma_f32_16x16x32_bf16(ca1, cb1, acc11, 0, 0, 0);
        ca0 = na0; ca1 = na1; cb0 = nb0; cb1 = nb1;
    }

    // bias per output col (n): two values per lane (fn=0,1)
    float bv[2] = {0.0f, 0.0f};
    if (d.bias) {
        bv[0] = d.bias[tn * 32 + lrow];
        bv[1] = d.bias[tn * 32 + 16 + lrow];
    }
    f32x4 acc[2][2] = {{acc00, acc01}, {acc10, acc11}};

    // C/D layout: col=lane&15, row=quad*4+reg (verified m89/m91)
    if (d.flags & 4) {                      // FS bf16 out (for h, WcT)
        const int K32o = d.N >> 5;
        u16* Co = (u16*)d.C;
        #pragma unroll
        for (int fm = 0; fm < 2; ++fm)
            #pragma unroll
            for (int fn = 0; fn < 2; ++fn)
                #pragma unroll
                for (int reg = 0; reg < 4; ++reg) {
                    const int m = tm * 32 + fm * 16 + quad * 4 + reg;
                    const int k = tn * 32 + fn * 16 + lrow;
                    float v = acc[fm][fn][reg] + bv[fn];
                    if (d.flags & 1) v = fmaxf(v, 0.0f);
                    size_t a = (((size_t)(m >> 4) * K32o + (k >> 5)) * 64
                                + ((k >> 3) & 3) * 16 + (m & 15)) * 8 + (k & 7);
                    Co[a] = f2bf(v);
                }
    } else if (d.flags & 2) {               // row-major bf16 (f0)
        u16* Co = (u16*)d.C;
        #pragma unroll
        for (int fm = 0; fm < 2; ++fm)
            #pragma unroll
            for (int fn = 0; fn < 2; ++fn)
                #pragma unroll
                for (int reg = 0; reg < 4; ++reg) {
                    const int m = tm * 32 + fm * 16 + quad * 4 + reg;
                    const int n = tn * 32 + fn * 16 + lrow;
                    float v = acc[fm][fn][reg] + bv[fn];
                    if (d.flags & 1) v = fmaxf(v, 0.0f);
                    Co[(size_t)m * d.N + n] = f2bf(v);
                }
    } else {                                // row-major fp32 (t)
        float* Co = (float*)d.C;
        #pragma unroll
        for (int fm = 0; fm < 2; ++fm)
            #pragma unroll
            for (int fn = 0; fn < 2; ++fn)
                #pragma unroll
                for (int reg = 0; reg < 4; ++reg) {
                    const int m = tm * 32 + fm * 16 + quad * 4 + reg;
                    const int n = tn * 32 + fn * 16 + lrow;
                    Co[(size_t)m * d.N + n] = acc[fm][fn][reg] + bv[fn];
                }
    }
}

// out[b,c] = sum_i f0[b,i] * t[b, i*2+c] + b_out[c]; one block per row b.
__global__ __launch_bounds__(256) void kron_reduce(
    const u16* __restrict__ f0, const float* __restrict__ t,
    const float* __restrict__ b_out, float* __restrict__ out)
{
    const int b = blockIdx.x;
    const int i = threadIdx.x;
    const float  v  = bf2f(f0[(size_t)b * 256 + i]);
    const float2 tv = ((const float2*)(t + (size_t)b * 512))[i];
    float p0 = v * tv.x;
    float p1 = v * tv.y;
    #pragma unroll
    for (int off = 32; off > 0; off >>= 1) {
        p0 += __shfl_down(p0, off);
        p1 += __shfl_down(p1, off);
    }
    __shared__ float s0[4], s1[4];
    const int wv = i >> 6;
    if ((i & 63) == 0) { s0[wv] = p0; s1[wv] = p1; }
    __syncthreads();
    if (i == 0) {
        out[(size_t)b * 2 + 0] = s0[0] + s0[1] + s0[2] + s0[3] + b_out[0];
        out[(size_t)b * 2 + 1] = s1[0] + s1[1] + s1[2] + s1[3] + b_out[1];
    }
}

extern "C" void kernel_launch(void* const* d_in, const int* in_sizes, int n_in,
                              void* d_out, int out_size, void* d_ws, size_t ws_size,
                              hipStream_t stream) {
    const float* x0     = (const float*)d_in[0];
    const float* x1     = (const float*)d_in[1];
    const float* W_feat = (const float*)d_in[2];
    const float* b_feat = (const float*)d_in[3];
    const float* W_br0  = (const float*)d_in[4];
    const float* b_br0  = (const float*)d_in[5];
    const float* W_br1  = (const float*)d_in[6];
    const float* b_br1  = (const float*)d_in[7];
    const float* W_out  = (const float*)d_in[8];
    const float* b_out  = (const float*)d_in[9];
    float* out = (float*)d_out;

    u16* ws   = (u16*)d_ws;
    u16* xb0  = ws;                    // FS 2048x1024
    u16* xb1  = xb0  + 2097152;
    u16* WfT  = xb1  + 2097152;        // FS-B 512x1024
    u16* Wb0T = WfT  + 524288;         // FS-B 256x512
    u16* WrT  = Wb0T + 131072;         // FS-A 512x256
    u16* Wb1c = WrT  + 131072;         // FS-B 512x256
    u16* WcT  = Wb1c + 131072;         // FS-B 512x512 (written by L1 Wc-gemm)
    u16* h0   = WcT  + 262144;         // FS 2048x512
    u16* h1   = h0   + 1048576;
    u16* f0   = h1   + 1048576;        // row-major bf16 2048x256
    float* t  = (float*)(f0 + 524288); // row-major fp32 2048x512
    float* bc = t + 1048576;           // 512

    dim3 blk(256);

    // 1) prep: pack everything + bc  (2498 blocks)
    prep<<<dim3(2498), blk, 0, stream>>>(
        x0, xb0, x1, xb1, W_feat, WfT, W_br0, Wb0T, W_out, WrT,
        W_br1, Wb1c, b_br1, bc);

    // 2) L1: h0, h1 (K=1024, relu, FS out) + WcT (K=256, FS out)
    GD g1a = { xb0, WfT,  b_feat,  h0,  32, 16, 512, 7 };   // 1024 waves
    GD g1b = { xb1, WfT,  b_feat,  h1,  32, 16, 512, 7 };   // 1024 waves
    GD g1c = { WrT, Wb1c, nullptr, WcT,  8, 16, 512, 6 };   // 256 waves
    gemm_wave<<<dim3(576), blk, 0, stream>>>(g1a, g1b, g1c, 1024, 2048);

    // 3) G2: f0 = h0 @ W_br0 + b_br0 (bf16 rm) ; t = h1 @ Wc + bc (fp32 rm)
    GD g2a = { h0, Wb0T, b_br0, f0, 16,  8, 256, 2 };       // 512 waves
    GD g2b = { h1, WcT,  bc,    t,  16, 16, 512, 0 };       // 1024 waves
    gemm_wave<<<dim3(384), blk, 0, stream>>>(g2a, g2b, g2b, 512, 1536);

    // 4) out
    kron_reduce<<<dim3(2048), blk, 0, stream>>>(f0, t, b_out, out);
}